// Round 9
// baseline (590.958 us; speedup 1.0000x reference)
//
#include <hip/hip_runtime.h>

// LightGCN propagation: out = mean(x0..x3), x_{k+1} = SpMM(COO, x_k)
// v9: (1) passA PA_CHUNK 4096->2048: LDS 45->24 KB, 3->6 blocks/CU occupancy;
//     (2) gcur_init2 -> memsetAsync + relative cursors; bucket_scan folded
//         into passB (shfl reduce) -> 9 launches -> 7;
//     (3) revert nt STORES in FUSE (measured WRITE +6MB regression); keep
//         nt loads (neutral). L3 gather excess not instruction-controllable.

#define N_USERS  100000
#define N_ITEMS  200000
#define N_NODES_ 300000
#define DIM      64
#define NNZ_     4000000
#define BSHIFT   10
#define NBUCKET  ((N_NODES_ + 1023) >> 10)                // 293
#define BCAP     14336                                    // slots per bucket region
#define PA_CHUNK 2048
#define PA_BLOCKS ((NNZ_ + PA_CHUNK - 1) / PA_CHUNK)      // 1954

// ---- non-temporal load wrappers ----
typedef float        f32x4 __attribute__((ext_vector_type(4)));
typedef unsigned int u32x4 __attribute__((ext_vector_type(4)));
typedef int          i32x2 __attribute__((ext_vector_type(2)));
__device__ __forceinline__ float4 ntload_f4(const float4* p) {
    f32x4 v = __builtin_nontemporal_load((const f32x4*)p);
    return make_float4(v.x, v.y, v.z, v.w);
}
__device__ __forceinline__ uint4 ntload_u4(const uint4* p) {
    u32x4 v = __builtin_nontemporal_load((const u32x4*)p);
    return make_uint4(v.x, v.y, v.z, v.w);
}
__device__ __forceinline__ int2 ntload_i2(const int2* p) {
    i32x2 v = __builtin_nontemporal_load((const i32x2*)p);
    return make_int2(v.x, v.y);
}

// ---- bf16 helpers (manual, RNE) ----
__device__ __forceinline__ unsigned short f2bf(float f) {
    unsigned u = __float_as_uint(f);
    unsigned r = 0x7fffu + ((u >> 16) & 1u);
    return (unsigned short)((u + r) >> 16);
}
__device__ __forceinline__ void fma8(float* acc, float v, uint4 r) {
    acc[0] = fmaf(v, __uint_as_float(r.x << 16), acc[0]);
    acc[1] = fmaf(v, __uint_as_float(r.x & 0xffff0000u), acc[1]);
    acc[2] = fmaf(v, __uint_as_float(r.y << 16), acc[2]);
    acc[3] = fmaf(v, __uint_as_float(r.y & 0xffff0000u), acc[3]);
    acc[4] = fmaf(v, __uint_as_float(r.z << 16), acc[4]);
    acc[5] = fmaf(v, __uint_as_float(r.z & 0xffff0000u), acc[5]);
    acc[6] = fmaf(v, __uint_as_float(r.w << 16), acc[6]);
    acc[7] = fmaf(v, __uint_as_float(r.w & 0xffff0000u), acc[7]);
}
__device__ __forceinline__ uint4 pack8(const float* f) {
    unsigned a = (unsigned)f2bf(f[0]) | ((unsigned)f2bf(f[1]) << 16);
    unsigned b = (unsigned)f2bf(f[2]) | ((unsigned)f2bf(f[3]) << 16);
    unsigned c = (unsigned)f2bf(f[4]) | ((unsigned)f2bf(f[5]) << 16);
    unsigned d = (unsigned)f2bf(f[6]) | ((unsigned)f2bf(f[7]) << 16);
    return make_uint4(a, b, c, d);
}
__device__ __forceinline__ void unpack8(float* f, uint4 r) {
    f[0] = __uint_as_float(r.x << 16); f[1] = __uint_as_float(r.x & 0xffff0000u);
    f[2] = __uint_as_float(r.y << 16); f[3] = __uint_as_float(r.y & 0xffff0000u);
    f[4] = __uint_as_float(r.z << 16); f[5] = __uint_as_float(r.z & 0xffff0000u);
    f[6] = __uint_as_float(r.w << 16); f[7] = __uint_as_float(r.w & 0xffff0000u);
}

// ---------------- init: Abf = bf16(concat(user,item)) ----------------
__global__ void init_bf(const float4* __restrict__ u, const float4* __restrict__ it,
                        uint4* __restrict__ Abf) {
    const int n_u = N_USERS * DIM / 8;   // 800000
    const int n_t = N_NODES_ * DIM / 8;  // 2400000
    int i = blockIdx.x * blockDim.x + threadIdx.x;
    if (i >= n_t) return;
    float4 a, b;
    if (i < n_u) { a = u[2 * i];           b = u[2 * i + 1]; }
    else         { int j = i - n_u; a = it[2 * j]; b = it[2 * j + 1]; }
    float f[8] = {a.x, a.y, a.z, a.w, b.x, b.y, b.z, b.w};
    Abf[i] = pack8(f);
}

// ---------------- pass A: block-local counting sort into row buckets ----------------
// v9: PA_CHUNK=2048 (LDS ~24 KB -> 6 blocks/CU). gcursor is zero-initialized
// (memset); atomicAdd returns a RELATIVE offset, absolute base = b*BCAP + rel.
// entry: lo = col | (row_local10 << 19), hi = val bits
__global__ __launch_bounds__(256) void passA(const int* __restrict__ rows,
                                             const int* __restrict__ cols,
                                             const float* __restrict__ vals,
                                             int* __restrict__ gcursor,
                                             int2* __restrict__ binned) {
    __shared__ int  hist[NBUCKET];            // counts, then reused as cursor
    __shared__ int  base_l[NBUCKET];          // exclusive scan of hist
    __shared__ int  gshift[NBUCKET];          // abs_base[b] - base_l[b]
    __shared__ int  sc[256];                  // block scan temp
    __shared__ int2 stage[PA_CHUNK];          // 16 KB: chunk sorted by bucket
    __shared__ unsigned short bIdA[PA_CHUNK]; // 4 KB: bucket id per staged slot

    int tid = threadIdx.x;
    int base = blockIdx.x * PA_CHUNK;
    int cnt = NNZ_ - base; if (cnt > PA_CHUNK) cnt = PA_CHUNK;

    for (int i = tid; i < NBUCKET; i += 256) hist[i] = 0;
    __syncthreads();

    int rr[8], cc[8], vv[8];
    #pragma unroll
    for (int k = 0; k < 8; ++k) {
        int i = tid + (k << 8);
        if (i < cnt) {
            int e = base + i;
            rr[k] = rows[e];
            cc[k] = cols[e];
            vv[k] = __float_as_int(vals[e]);
            atomicAdd(&hist[rr[k] >> BSHIFT], 1);
        } else rr[k] = -1;
    }
    __syncthreads();

    int i0 = 2 * tid, i1 = 2 * tid + 1;
    int c0 = (i0 < NBUCKET) ? hist[i0] : 0;
    int c1 = (i1 < NBUCKET) ? hist[i1] : 0;
    sc[tid] = c0 + c1;
    __syncthreads();
    for (int off = 1; off < 256; off <<= 1) {
        int t = (tid >= off) ? sc[tid - off] : 0;
        __syncthreads();
        sc[tid] += t;
        __syncthreads();
    }
    int excl = (tid == 0) ? 0 : sc[tid - 1];
    if (i0 < NBUCKET) {
        base_l[i0] = excl;
        int g0 = c0 ? atomicAdd(&gcursor[i0], c0) : 0;   // relative
        gshift[i0] = i0 * BCAP + g0 - excl;
        hist[i0] = 0;
    }
    if (i1 < NBUCKET) {
        base_l[i1] = excl + c0;
        int g1 = c1 ? atomicAdd(&gcursor[i1], c1) : 0;   // relative
        gshift[i1] = i1 * BCAP + g1 - (excl + c0);
        hist[i1] = 0;
    }
    __syncthreads();

    #pragma unroll
    for (int k = 0; k < 8; ++k) {
        if (rr[k] >= 0) {
            int b = rr[k] >> BSHIFT;
            int kk = atomicAdd(&hist[b], 1);
            int pos = base_l[b] + kk;
            stage[pos] = make_int2(cc[k] | ((rr[k] & 1023) << 19), vv[k]);
            bIdA[pos] = (unsigned short)b;
        }
    }
    __syncthreads();

    #pragma unroll
    for (int k = 0; k < 8; ++k) {
        int i = tid + (k << 8);
        if (i < cnt) binned[gshift[bIdA[i]] + i] = stage[i];
    }
}

// ---------------- pass B: within-bucket row sort + per-row CSR offsets ----------------
// v9: computes its own CSR base (csr0 = sum of counts of buckets < b) via a
// 2-barrier shfl reduce over gcursor (bucket_scan kernel eliminated).
__global__ __launch_bounds__(1024) void passB(const int* __restrict__ gcursor,
                                              const int2* __restrict__ binned,
                                              int* __restrict__ row_start,
                                              int2* __restrict__ sedge) {
    __shared__ int lcnt[1024];
    __shared__ int wsum[17];
    int b = blockIdx.x;
    int t = threadIdx.x;
    int lane = t & 63;
    int wid = t >> 6;                     // 16 waves
    int base = b * BCAP;
    int cnt = gcursor[b];                 // edges in this bucket (count)

    // csr0 = sum of gcursor[j] for j < b (2 barriers, shfl reduce)
    int c = (t < b) ? gcursor[t] : 0;     // b <= 292 < NBUCKET, t<b safe
    #pragma unroll
    for (int off = 1; off < 64; off <<= 1) c += __shfl_xor(c, off);
    if (lane == 0) wsum[wid] = c;
    __syncthreads();
    if (t < 16) {
        int s = wsum[t];
        #pragma unroll
        for (int off = 1; off < 16; off <<= 1) s += __shfl_xor(s, off);
        if (t == 0) wsum[16] = s;
    }
    lcnt[t] = 0;
    __syncthreads();
    int csr0 = wsum[16];
    if (b == NBUCKET - 1 && t == 0) row_start[N_NODES_] = NNZ_;

    int lo[14], hv[14];
    #pragma unroll
    for (int k = 0; k < 14; ++k) {
        int i = t + (k << 10);
        if (i < cnt) {
            int2 p = ntload_i2(&binned[base + i]);
            lo[k] = p.x; hv[k] = p.y;
            atomicAdd(&lcnt[((unsigned)p.x >> 19) & 1023], 1);
        } else lo[k] = -1;                // bit31 never set in real entries
    }
    __syncthreads();

    // shfl-based inclusive scan over the 1024 counts
    int v = lcnt[t];
    int sv = v;
    #pragma unroll
    for (int off = 1; off < 64; off <<= 1) {
        int tmp = __shfl_up(sv, off);
        if (lane >= off) sv += tmp;
    }
    if (lane == 63) wsum[wid] = sv;       // wave totals
    __syncthreads();
    if (t < 16) {
        int ws = wsum[t];
        #pragma unroll
        for (int off = 1; off < 16; off <<= 1) {
            int tmp = __shfl_up(ws, off);
            if (t >= off) ws += tmp;
        }
        wsum[t] = ws;                     // inclusive wave-prefix
    }
    __syncthreads();
    int wbase = (wid == 0) ? 0 : wsum[wid - 1];
    int excl = wbase + sv - v;            // exclusive prefix for row t

    int gr = (b << BSHIFT) + t;
    if (gr < N_NODES_) row_start[gr] = csr0 + excl;
    lcnt[t] = excl;                       // reuse as placement cursor
    __syncthreads();

    #pragma unroll
    for (int k = 0; k < 14; ++k) {
        if (lo[k] >= 0) {
            int rl = ((unsigned)lo[k] >> 19) & 1023;
            int pos = atomicAdd(&lcnt[rl], 1);
            sedge[csr0 + pos] = make_int2(lo[k] & 0x7ffff, hv[k]);
        }
    }
}

// ---------------- CSR SpMM bf16, group-per-row ----------------
// 8-lane group owns one row; wave = 8 rows; block(256) = 32 rows.
// FUSE: out = (x0 + x1 + x2 + acc) * 0.25 written fp32 directly.
// nt loads on single-use streams; stores are NORMAL (nt stores measured +6MB WRITE).
template<bool FUSE>
__global__ __launch_bounds__(256) void spmm_bf_t(const int* __restrict__ row_start,
                                                 const int2* __restrict__ sedge,
                                                 const uint4* __restrict__ x,
                                                 uint4* __restrict__ y,
                                                 const float4* __restrict__ u,
                                                 const float4* __restrict__ it,
                                                 const uint4* __restrict__ x1,
                                                 const uint4* __restrict__ x2,
                                                 float4* __restrict__ out) {
    int w = blockIdx.x * 32 + (threadIdx.x >> 3);   // row per 8-lane group
    int d = threadIdx.x & 7;                        // dim slice (8 elems)
    int s = row_start[w];
    int e = row_start[w + 1];
    float acc[8] = {0.f, 0.f, 0.f, 0.f, 0.f, 0.f, 0.f, 0.f};
    int i = s;
    for (; i + 1 < e; i += 2) {
        int2 p0 = sedge[i];
        int2 p1 = sedge[i + 1];
        uint4 r0 = x[((unsigned)p0.x << 3) + d];
        uint4 r1 = x[((unsigned)p1.x << 3) + d];
        fma8(acc, __int_as_float(p0.y), r0);
        fma8(acc, __int_as_float(p1.y), r1);
    }
    if (i < e) {
        int2 p0 = sedge[i];
        uint4 r0 = x[((unsigned)p0.x << 3) + d];
        fma8(acc, __int_as_float(p0.y), r0);
    }
    if (!FUSE) {
        y[(size_t)w * 8 + d] = pack8(acc);
    } else {
        const float4* src = (w < N_USERS) ? (u + (size_t)w * 16)
                                          : (it + (size_t)(w - N_USERS) * 16);
        float4 a  = ntload_f4(&src[2 * d]);
        float4 b2 = ntload_f4(&src[2 * d + 1]);
        float f0[8] = {a.x, a.y, a.z, a.w, b2.x, b2.y, b2.z, b2.w};
        float f1[8], f2[8];
        unpack8(f1, ntload_u4(&x1[(size_t)w * 8 + d]));
        unpack8(f2, x2[(size_t)w * 8 + d]);
        float o[8];
        #pragma unroll
        for (int k = 0; k < 8; ++k) o[k] = (f0[k] + f1[k] + f2[k] + acc[k]) * 0.25f;
        out[(size_t)w * 16 + 2 * d]     = make_float4(o[0], o[1], o[2], o[3]);
        out[(size_t)w * 16 + 2 * d + 1] = make_float4(o[4], o[5], o[6], o[7]);
    }
}

extern "C" void kernel_launch(void* const* d_in, const int* in_sizes, int n_in,
                              void* d_out, int out_size, void* d_ws, size_t ws_size,
                              hipStream_t stream) {
    const float* user_emb = (const float*)d_in[0];
    const float* item_emb = (const float*)d_in[1];
    const int*   rows     = (const int*)d_in[2];
    const int*   cols     = (const int*)d_in[3];
    const float* vals     = (const float*)d_in[4];
    float* out = (float*)d_out;

    const size_t nE = (size_t)N_NODES_ * DIM;   // 19.2M elems
    unsigned short* Abf = (unsigned short*)d_ws;            // 38.4 MB (x0)
    unsigned short* Bbf = Abf + nE;                         // 38.4 MB (x1)
    unsigned short* Cbf = Bbf + nE;                         // 38.4 MB (x2)
    int* row_start   = (int*)(Cbf + nE);                    // N+2 ints
    int* gcursor     = row_start + (N_NODES_ + 2);          // 512
    int2* binned = (int2*)(gcursor + 512);                  // 293*14336*8 = 33.6 MB
    int2* sedge  = binned + (size_t)NBUCKET * BCAP;         // 32 MB

    const int n_t8 = (int)(nE / 8);                         // 2.4M
    const int ew_grid   = (n_t8 + 255) / 256;               // 9375
    const int spmm_grid = N_NODES_ / 32;                    // 9375 (exact)

    // ---- build CSR: fixed-capacity bins (relative cursors, zero-init) ----
    hipMemsetAsync(gcursor, 0, NBUCKET * sizeof(int), stream);
    passA<<<PA_BLOCKS, 256, 0, stream>>>(rows, cols, vals, gcursor, binned);
    passB<<<NBUCKET, 1024, 0, stream>>>(gcursor, binned, row_start, sedge);

    // ---- x0 (bf16) ----
    init_bf<<<ew_grid, 256, 0, stream>>>((const float4*)user_emb, (const float4*)item_emb,
                                         (uint4*)Abf);
    // ---- 3 layers; layer 3 fuses the mean epilogue ----
    spmm_bf_t<false><<<spmm_grid, 256, 0, stream>>>(row_start, sedge, (const uint4*)Abf,
                                                    (uint4*)Bbf, nullptr, nullptr,
                                                    nullptr, nullptr, nullptr);
    spmm_bf_t<false><<<spmm_grid, 256, 0, stream>>>(row_start, sedge, (const uint4*)Bbf,
                                                    (uint4*)Cbf, nullptr, nullptr,
                                                    nullptr, nullptr, nullptr);
    spmm_bf_t<true><<<spmm_grid, 256, 0, stream>>>(row_start, sedge, (const uint4*)Cbf,
                                                   nullptr,
                                                   (const float4*)user_emb,
                                                   (const float4*)item_emb,
                                                   (const uint4*)Bbf, (const uint4*)Cbf,
                                                   (float4*)out);
}

// Round 13
// 547.381 us; speedup vs baseline: 1.0796x; 1.0796x over previous
//
#include <hip/hip_runtime.h>

// LightGCN propagation: out = mean(x0..x3), x_{k+1} = SpMM(COO, x_k)
// v10: REVERT v9's PA_CHUNK 2048 -> back to 4096 (v9 regressed passA 85->133us:
//      per-block fixed cost [293-slot hist zero + scan + reservation] doubled,
//      flush runs halved to 56B. passA is phase-latency-bound, not wave-bound).
//      Kept from v9: relative cursors + memset (no gcur_init2), bucket_scan
//      folded into passB, normal stores in FUSE (nt stores regressed WRITE).
// (resubmitted verbatim; broker timeouts r10/r11/r12)

#define N_USERS  100000
#define N_ITEMS  200000
#define N_NODES_ 300000
#define DIM      64
#define NNZ_     4000000
#define BSHIFT   10
#define NBUCKET  ((N_NODES_ + 1023) >> 10)                // 293
#define BCAP     14336                                    // slots per bucket region
#define PA_CHUNK 4096
#define PA_BLOCKS ((NNZ_ + PA_CHUNK - 1) / PA_CHUNK)      // 977

// ---- non-temporal load wrappers ----
typedef float        f32x4 __attribute__((ext_vector_type(4)));
typedef unsigned int u32x4 __attribute__((ext_vector_type(4)));
typedef int          i32x2 __attribute__((ext_vector_type(2)));
__device__ __forceinline__ float4 ntload_f4(const float4* p) {
    f32x4 v = __builtin_nontemporal_load((const f32x4*)p);
    return make_float4(v.x, v.y, v.z, v.w);
}
__device__ __forceinline__ uint4 ntload_u4(const uint4* p) {
    u32x4 v = __builtin_nontemporal_load((const u32x4*)p);
    return make_uint4(v.x, v.y, v.z, v.w);
}
__device__ __forceinline__ int2 ntload_i2(const int2* p) {
    i32x2 v = __builtin_nontemporal_load((const i32x2*)p);
    return make_int2(v.x, v.y);
}

// ---- bf16 helpers (manual, RNE) ----
__device__ __forceinline__ unsigned short f2bf(float f) {
    unsigned u = __float_as_uint(f);
    unsigned r = 0x7fffu + ((u >> 16) & 1u);
    return (unsigned short)((u + r) >> 16);
}
__device__ __forceinline__ void fma8(float* acc, float v, uint4 r) {
    acc[0] = fmaf(v, __uint_as_float(r.x << 16), acc[0]);
    acc[1] = fmaf(v, __uint_as_float(r.x & 0xffff0000u), acc[1]);
    acc[2] = fmaf(v, __uint_as_float(r.y << 16), acc[2]);
    acc[3] = fmaf(v, __uint_as_float(r.y & 0xffff0000u), acc[3]);
    acc[4] = fmaf(v, __uint_as_float(r.z << 16), acc[4]);
    acc[5] = fmaf(v, __uint_as_float(r.z & 0xffff0000u), acc[5]);
    acc[6] = fmaf(v, __uint_as_float(r.w << 16), acc[6]);
    acc[7] = fmaf(v, __uint_as_float(r.w & 0xffff0000u), acc[7]);
}
__device__ __forceinline__ uint4 pack8(const float* f) {
    unsigned a = (unsigned)f2bf(f[0]) | ((unsigned)f2bf(f[1]) << 16);
    unsigned b = (unsigned)f2bf(f[2]) | ((unsigned)f2bf(f[3]) << 16);
    unsigned c = (unsigned)f2bf(f[4]) | ((unsigned)f2bf(f[5]) << 16);
    unsigned d = (unsigned)f2bf(f[6]) | ((unsigned)f2bf(f[7]) << 16);
    return make_uint4(a, b, c, d);
}
__device__ __forceinline__ void unpack8(float* f, uint4 r) {
    f[0] = __uint_as_float(r.x << 16); f[1] = __uint_as_float(r.x & 0xffff0000u);
    f[2] = __uint_as_float(r.y << 16); f[3] = __uint_as_float(r.y & 0xffff0000u);
    f[4] = __uint_as_float(r.z << 16); f[5] = __uint_as_float(r.z & 0xffff0000u);
    f[6] = __uint_as_float(r.w << 16); f[7] = __uint_as_float(r.w & 0xffff0000u);
}

// ---------------- init: Abf = bf16(concat(user,item)) ----------------
__global__ void init_bf(const float4* __restrict__ u, const float4* __restrict__ it,
                        uint4* __restrict__ Abf) {
    const int n_u = N_USERS * DIM / 8;   // 800000
    const int n_t = N_NODES_ * DIM / 8;  // 2400000
    int i = blockIdx.x * blockDim.x + threadIdx.x;
    if (i >= n_t) return;
    float4 a, b;
    if (i < n_u) { a = u[2 * i];           b = u[2 * i + 1]; }
    else         { int j = i - n_u; a = it[2 * j]; b = it[2 * j + 1]; }
    float f[8] = {a.x, a.y, a.z, a.w, b.x, b.y, b.z, b.w};
    Abf[i] = pack8(f);
}

// ---------------- pass A: block-local counting sort into row buckets ----------------
// gcursor zero-initialized (memset); atomicAdd returns a RELATIVE offset,
// absolute base = b*BCAP + rel. entry: lo = col | (row_local10 << 19), hi = val
__global__ __launch_bounds__(256) void passA(const int* __restrict__ rows,
                                             const int* __restrict__ cols,
                                             const float* __restrict__ vals,
                                             int* __restrict__ gcursor,
                                             int2* __restrict__ binned) {
    __shared__ int  hist[NBUCKET];            // counts, then reused as cursor
    __shared__ int  base_l[NBUCKET];          // exclusive scan of hist
    __shared__ int  gshift[NBUCKET];          // abs_base[b] - base_l[b]
    __shared__ int  sc[256];                  // block scan temp
    __shared__ int2 stage[PA_CHUNK];          // 32 KB: chunk sorted by bucket
    __shared__ unsigned short bIdA[PA_CHUNK]; // 8 KB: bucket id per staged slot

    int tid = threadIdx.x;
    int base = blockIdx.x * PA_CHUNK;
    int cnt = NNZ_ - base; if (cnt > PA_CHUNK) cnt = PA_CHUNK;

    for (int i = tid; i < NBUCKET; i += 256) hist[i] = 0;
    __syncthreads();

    int rr[16], cc[16], vv[16];
    #pragma unroll
    for (int k = 0; k < 16; ++k) {
        int i = tid + (k << 8);
        if (i < cnt) {
            int e = base + i;
            rr[k] = rows[e];
            cc[k] = cols[e];
            vv[k] = __float_as_int(vals[e]);
            atomicAdd(&hist[rr[k] >> BSHIFT], 1);
        } else rr[k] = -1;
    }
    __syncthreads();

    int i0 = 2 * tid, i1 = 2 * tid + 1;
    int c0 = (i0 < NBUCKET) ? hist[i0] : 0;
    int c1 = (i1 < NBUCKET) ? hist[i1] : 0;
    sc[tid] = c0 + c1;
    __syncthreads();
    for (int off = 1; off < 256; off <<= 1) {
        int t = (tid >= off) ? sc[tid - off] : 0;
        __syncthreads();
        sc[tid] += t;
        __syncthreads();
    }
    int excl = (tid == 0) ? 0 : sc[tid - 1];
    if (i0 < NBUCKET) {
        base_l[i0] = excl;
        int g0 = c0 ? atomicAdd(&gcursor[i0], c0) : 0;   // relative
        gshift[i0] = i0 * BCAP + g0 - excl;
        hist[i0] = 0;
    }
    if (i1 < NBUCKET) {
        base_l[i1] = excl + c0;
        int g1 = c1 ? atomicAdd(&gcursor[i1], c1) : 0;   // relative
        gshift[i1] = i1 * BCAP + g1 - (excl + c0);
        hist[i1] = 0;
    }
    __syncthreads();

    #pragma unroll
    for (int k = 0; k < 16; ++k) {
        if (rr[k] >= 0) {
            int b = rr[k] >> BSHIFT;
            int kk = atomicAdd(&hist[b], 1);
            int pos = base_l[b] + kk;
            stage[pos] = make_int2(cc[k] | ((rr[k] & 1023) << 19), vv[k]);
            bIdA[pos] = (unsigned short)b;
        }
    }
    __syncthreads();

    #pragma unroll
    for (int k = 0; k < 16; ++k) {
        int i = tid + (k << 8);
        if (i < cnt) binned[gshift[bIdA[i]] + i] = stage[i];
    }
}

// ---------------- pass B: within-bucket row sort + per-row CSR offsets ----------------
// Computes its own CSR base (csr0 = sum of counts of buckets < b) via a
// 2-barrier shfl reduce over gcursor (bucket_scan kernel eliminated).
__global__ __launch_bounds__(1024) void passB(const int* __restrict__ gcursor,
                                              const int2* __restrict__ binned,
                                              int* __restrict__ row_start,
                                              int2* __restrict__ sedge) {
    __shared__ int lcnt[1024];
    __shared__ int wsum[17];
    int b = blockIdx.x;
    int t = threadIdx.x;
    int lane = t & 63;
    int wid = t >> 6;                     // 16 waves
    int base = b * BCAP;
    int cnt = gcursor[b];                 // edges in this bucket (count)

    // csr0 = sum of gcursor[j] for j < b (2 barriers, shfl reduce)
    int c = (t < b) ? gcursor[t] : 0;     // b <= 292 < NBUCKET, t<b safe
    #pragma unroll
    for (int off = 1; off < 64; off <<= 1) c += __shfl_xor(c, off);
    if (lane == 0) wsum[wid] = c;
    __syncthreads();
    if (t < 16) {
        int s = wsum[t];
        #pragma unroll
        for (int off = 1; off < 16; off <<= 1) s += __shfl_xor(s, off);
        if (t == 0) wsum[16] = s;
    }
    lcnt[t] = 0;
    __syncthreads();
    int csr0 = wsum[16];
    if (b == NBUCKET - 1 && t == 0) row_start[N_NODES_] = NNZ_;

    int lo[14], hv[14];
    #pragma unroll
    for (int k = 0; k < 14; ++k) {
        int i = t + (k << 10);
        if (i < cnt) {
            int2 p = ntload_i2(&binned[base + i]);
            lo[k] = p.x; hv[k] = p.y;
            atomicAdd(&lcnt[((unsigned)p.x >> 19) & 1023], 1);
        } else lo[k] = -1;                // bit31 never set in real entries
    }
    __syncthreads();

    // shfl-based inclusive scan over the 1024 counts
    int v = lcnt[t];
    int sv = v;
    #pragma unroll
    for (int off = 1; off < 64; off <<= 1) {
        int tmp = __shfl_up(sv, off);
        if (lane >= off) sv += tmp;
    }
    if (lane == 63) wsum[wid] = sv;       // wave totals
    __syncthreads();
    if (t < 16) {
        int ws = wsum[t];
        #pragma unroll
        for (int off = 1; off < 16; off <<= 1) {
            int tmp = __shfl_up(ws, off);
            if (t >= off) ws += tmp;
        }
        wsum[t] = ws;                     // inclusive wave-prefix
    }
    __syncthreads();
    int wbase = (wid == 0) ? 0 : wsum[wid - 1];
    int excl = wbase + sv - v;            // exclusive prefix for row t

    int gr = (b << BSHIFT) + t;
    if (gr < N_NODES_) row_start[gr] = csr0 + excl;
    lcnt[t] = excl;                       // reuse as placement cursor
    __syncthreads();

    #pragma unroll
    for (int k = 0; k < 14; ++k) {
        if (lo[k] >= 0) {
            int rl = ((unsigned)lo[k] >> 19) & 1023;
            int pos = atomicAdd(&lcnt[rl], 1);
            sedge[csr0 + pos] = make_int2(lo[k] & 0x7ffff, hv[k]);
        }
    }
}

// ---------------- CSR SpMM bf16, group-per-row ----------------
// 8-lane group owns one row; wave = 8 rows; block(256) = 32 rows.
// FUSE: out = (x0 + x1 + x2 + acc) * 0.25 written fp32 directly.
// nt loads on single-use streams; stores NORMAL.
template<bool FUSE>
__global__ __launch_bounds__(256) void spmm_bf_t(const int* __restrict__ row_start,
                                                 const int2* __restrict__ sedge,
                                                 const uint4* __restrict__ x,
                                                 uint4* __restrict__ y,
                                                 const float4* __restrict__ u,
                                                 const float4* __restrict__ it,
                                                 const uint4* __restrict__ x1,
                                                 const uint4* __restrict__ x2,
                                                 float4* __restrict__ out) {
    int w = blockIdx.x * 32 + (threadIdx.x >> 3);   // row per 8-lane group
    int d = threadIdx.x & 7;                        // dim slice (8 elems)
    int s = row_start[w];
    int e = row_start[w + 1];
    float acc[8] = {0.f, 0.f, 0.f, 0.f, 0.f, 0.f, 0.f, 0.f};
    int i = s;
    for (; i + 1 < e; i += 2) {
        int2 p0 = sedge[i];
        int2 p1 = sedge[i + 1];
        uint4 r0 = x[((unsigned)p0.x << 3) + d];
        uint4 r1 = x[((unsigned)p1.x << 3) + d];
        fma8(acc, __int_as_float(p0.y), r0);
        fma8(acc, __int_as_float(p1.y), r1);
    }
    if (i < e) {
        int2 p0 = sedge[i];
        uint4 r0 = x[((unsigned)p0.x << 3) + d];
        fma8(acc, __int_as_float(p0.y), r0);
    }
    if (!FUSE) {
        y[(size_t)w * 8 + d] = pack8(acc);
    } else {
        const float4* src = (w < N_USERS) ? (u + (size_t)w * 16)
                                          : (it + (size_t)(w - N_USERS) * 16);
        float4 a  = ntload_f4(&src[2 * d]);
        float4 b2 = ntload_f4(&src[2 * d + 1]);
        float f0[8] = {a.x, a.y, a.z, a.w, b2.x, b2.y, b2.z, b2.w};
        float f1[8], f2[8];
        unpack8(f1, ntload_u4(&x1[(size_t)w * 8 + d]));
        unpack8(f2, x2[(size_t)w * 8 + d]);
        float o[8];
        #pragma unroll
        for (int k = 0; k < 8; ++k) o[k] = (f0[k] + f1[k] + f2[k] + acc[k]) * 0.25f;
        out[(size_t)w * 16 + 2 * d]     = make_float4(o[0], o[1], o[2], o[3]);
        out[(size_t)w * 16 + 2 * d + 1] = make_float4(o[4], o[5], o[6], o[7]);
    }
}

extern "C" void kernel_launch(void* const* d_in, const int* in_sizes, int n_in,
                              void* d_out, int out_size, void* d_ws, size_t ws_size,
                              hipStream_t stream) {
    const float* user_emb = (const float*)d_in[0];
    const float* item_emb = (const float*)d_in[1];
    const int*   rows     = (const int*)d_in[2];
    const int*   cols     = (const int*)d_in[3];
    const float* vals     = (const float*)d_in[4];
    float* out = (float*)d_out;

    const size_t nE = (size_t)N_NODES_ * DIM;   // 19.2M elems
    unsigned short* Abf = (unsigned short*)d_ws;            // 38.4 MB (x0)
    unsigned short* Bbf = Abf + nE;                         // 38.4 MB (x1)
    unsigned short* Cbf = Bbf + nE;                         // 38.4 MB (x2)
    int* row_start   = (int*)(Cbf + nE);                    // N+2 ints
    int* gcursor     = row_start + (N_NODES_ + 2);          // 512
    int2* binned = (int2*)(gcursor + 512);                  // 293*14336*8 = 33.6 MB
    int2* sedge  = binned + (size_t)NBUCKET * BCAP;         // 32 MB

    const int n_t8 = (int)(nE / 8);                         // 2.4M
    const int ew_grid   = (n_t8 + 255) / 256;               // 9375
    const int spmm_grid = N_NODES_ / 32;                    // 9375 (exact)

    // ---- build CSR: fixed-capacity bins (relative cursors, zero-init) ----
    hipMemsetAsync(gcursor, 0, NBUCKET * sizeof(int), stream);
    passA<<<PA_BLOCKS, 256, 0, stream>>>(rows, cols, vals, gcursor, binned);
    passB<<<NBUCKET, 1024, 0, stream>>>(gcursor, binned, row_start, sedge);

    // ---- x0 (bf16) ----
    init_bf<<<ew_grid, 256, 0, stream>>>((const float4*)user_emb, (const float4*)item_emb,
                                         (uint4*)Abf);
    // ---- 3 layers; layer 3 fuses the mean epilogue ----
    spmm_bf_t<false><<<spmm_grid, 256, 0, stream>>>(row_start, sedge, (const uint4*)Abf,
                                                    (uint4*)Bbf, nullptr, nullptr,
                                                    nullptr, nullptr, nullptr);
    spmm_bf_t<false><<<spmm_grid, 256, 0, stream>>>(row_start, sedge, (const uint4*)Bbf,
                                                    (uint4*)Cbf, nullptr, nullptr,
                                                    nullptr, nullptr, nullptr);
    spmm_bf_t<true><<<spmm_grid, 256, 0, stream>>>(row_start, sedge, (const uint4*)Cbf,
                                                   nullptr,
                                                   (const float4*)user_emb,
                                                   (const float4*)item_emb,
                                                   (const uint4*)Bbf, (const uint4*)Cbf,
                                                   (float4*)out);
}

// Round 16
// 514.437 us; speedup vs baseline: 1.1487x; 1.0640x over previous
//
#include <hip/hip_runtime.h>

// LightGCN propagation: out = mean(x0..x3), x_{k+1} = SpMM(COO, x_k)
// v11: (1) passA latency cut: 512 threads (all phase iteration counts halved,
//          LDS unchanged ~44.5KB -> 3 blocks/CU) + shfl-based bucket scan
//          (16 barriers -> 3). Attacks r9 diagnosis: phase-latency-bound.
//      (2) spmm edge-loop unroll x4 (deeper gather ILP; VALU 23%, BW 61% ->
//          dependent-chain-limited).
// (resubmitted verbatim; broker timeouts r14/r15)

#define N_USERS  100000
#define N_ITEMS  200000
#define N_NODES_ 300000
#define DIM      64
#define NNZ_     4000000
#define BSHIFT   10
#define NBUCKET  ((N_NODES_ + 1023) >> 10)                // 293
#define BCAP     14336                                    // slots per bucket region
#define PA_CHUNK 4096
#define PA_BLOCKS ((NNZ_ + PA_CHUNK - 1) / PA_CHUNK)      // 977

// ---- non-temporal load wrappers ----
typedef float        f32x4 __attribute__((ext_vector_type(4)));
typedef unsigned int u32x4 __attribute__((ext_vector_type(4)));
typedef int          i32x2 __attribute__((ext_vector_type(2)));
__device__ __forceinline__ float4 ntload_f4(const float4* p) {
    f32x4 v = __builtin_nontemporal_load((const f32x4*)p);
    return make_float4(v.x, v.y, v.z, v.w);
}
__device__ __forceinline__ uint4 ntload_u4(const uint4* p) {
    u32x4 v = __builtin_nontemporal_load((const u32x4*)p);
    return make_uint4(v.x, v.y, v.z, v.w);
}
__device__ __forceinline__ int2 ntload_i2(const int2* p) {
    i32x2 v = __builtin_nontemporal_load((const i32x2*)p);
    return make_int2(v.x, v.y);
}

// ---- bf16 helpers (manual, RNE) ----
__device__ __forceinline__ unsigned short f2bf(float f) {
    unsigned u = __float_as_uint(f);
    unsigned r = 0x7fffu + ((u >> 16) & 1u);
    return (unsigned short)((u + r) >> 16);
}
__device__ __forceinline__ void fma8(float* acc, float v, uint4 r) {
    acc[0] = fmaf(v, __uint_as_float(r.x << 16), acc[0]);
    acc[1] = fmaf(v, __uint_as_float(r.x & 0xffff0000u), acc[1]);
    acc[2] = fmaf(v, __uint_as_float(r.y << 16), acc[2]);
    acc[3] = fmaf(v, __uint_as_float(r.y & 0xffff0000u), acc[3]);
    acc[4] = fmaf(v, __uint_as_float(r.z << 16), acc[4]);
    acc[5] = fmaf(v, __uint_as_float(r.z & 0xffff0000u), acc[5]);
    acc[6] = fmaf(v, __uint_as_float(r.w << 16), acc[6]);
    acc[7] = fmaf(v, __uint_as_float(r.w & 0xffff0000u), acc[7]);
}
__device__ __forceinline__ uint4 pack8(const float* f) {
    unsigned a = (unsigned)f2bf(f[0]) | ((unsigned)f2bf(f[1]) << 16);
    unsigned b = (unsigned)f2bf(f[2]) | ((unsigned)f2bf(f[3]) << 16);
    unsigned c = (unsigned)f2bf(f[4]) | ((unsigned)f2bf(f[5]) << 16);
    unsigned d = (unsigned)f2bf(f[6]) | ((unsigned)f2bf(f[7]) << 16);
    return make_uint4(a, b, c, d);
}
__device__ __forceinline__ void unpack8(float* f, uint4 r) {
    f[0] = __uint_as_float(r.x << 16); f[1] = __uint_as_float(r.x & 0xffff0000u);
    f[2] = __uint_as_float(r.y << 16); f[3] = __uint_as_float(r.y & 0xffff0000u);
    f[4] = __uint_as_float(r.z << 16); f[5] = __uint_as_float(r.z & 0xffff0000u);
    f[6] = __uint_as_float(r.w << 16); f[7] = __uint_as_float(r.w & 0xffff0000u);
}

// ---------------- init: Abf = bf16(concat(user,item)) ----------------
__global__ void init_bf(const float4* __restrict__ u, const float4* __restrict__ it,
                        uint4* __restrict__ Abf) {
    const int n_u = N_USERS * DIM / 8;   // 800000
    const int n_t = N_NODES_ * DIM / 8;  // 2400000
    int i = blockIdx.x * blockDim.x + threadIdx.x;
    if (i >= n_t) return;
    float4 a, b;
    if (i < n_u) { a = u[2 * i];           b = u[2 * i + 1]; }
    else         { int j = i - n_u; a = it[2 * j]; b = it[2 * j + 1]; }
    float f[8] = {a.x, a.y, a.z, a.w, b.x, b.y, b.z, b.w};
    Abf[i] = pack8(f);
}

// ---------------- pass A: block-local counting sort into row buckets ----------------
// v11: 512 threads (rr[8]), shfl bucket scan (3 barriers). gcursor zero-init;
// atomicAdd returns RELATIVE offset, absolute = b*BCAP + rel.
// entry: lo = col | (row_local10 << 19), hi = val bits
__global__ __launch_bounds__(512) void passA(const int* __restrict__ rows,
                                             const int* __restrict__ cols,
                                             const float* __restrict__ vals,
                                             int* __restrict__ gcursor,
                                             int2* __restrict__ binned) {
    __shared__ int  hist[NBUCKET];            // counts, then reused as cursor
    __shared__ int  base_l[NBUCKET];          // exclusive scan of hist
    __shared__ int  gshift[NBUCKET];          // abs_base[b] - base_l[b]
    __shared__ int  wsum[8];                  // wave totals for shfl scan
    __shared__ int2 stage[PA_CHUNK];          // 32 KB: chunk sorted by bucket
    __shared__ unsigned short bIdA[PA_CHUNK]; // 8 KB: bucket id per staged slot

    int tid = threadIdx.x;
    int lane = tid & 63;
    int wid = tid >> 6;                       // 8 waves
    int base = blockIdx.x * PA_CHUNK;
    int cnt = NNZ_ - base; if (cnt > PA_CHUNK) cnt = PA_CHUNK;

    for (int i = tid; i < NBUCKET; i += 512) hist[i] = 0;
    __syncthreads();

    // load chunk into registers + LDS histogram
    int rr[8], cc[8], vv[8];
    #pragma unroll
    for (int k = 0; k < 8; ++k) {
        int i = tid + (k << 9);
        if (i < cnt) {
            int e = base + i;
            rr[k] = rows[e];
            cc[k] = cols[e];
            vv[k] = __float_as_int(vals[e]);
            atomicAdd(&hist[rr[k] >> BSHIFT], 1);
        } else rr[k] = -1;
    }
    __syncthreads();

    // shfl-based exclusive scan, 1 bucket per thread (NBUCKET=293 < 512)
    int cb = (tid < NBUCKET) ? hist[tid] : 0;
    int sv = cb;
    #pragma unroll
    for (int off = 1; off < 64; off <<= 1) {
        int tmp = __shfl_up(sv, off);
        if (lane >= off) sv += tmp;
    }
    if (lane == 63) wsum[wid] = sv;
    __syncthreads();
    if (tid < 8) {
        int ws = wsum[tid];
        #pragma unroll
        for (int off = 1; off < 8; off <<= 1) {
            int tmp = __shfl_up(ws, off);
            if (tid >= off) ws += tmp;
        }
        wsum[tid] = ws;                        // inclusive wave-prefix
    }
    __syncthreads();
    int wbase = wid ? wsum[wid - 1] : 0;
    int excl = wbase + sv - cb;               // exclusive prefix for bucket tid
    if (tid < NBUCKET) {
        base_l[tid] = excl;
        int g = cb ? atomicAdd(&gcursor[tid], cb) : 0;   // relative
        gshift[tid] = tid * BCAP + g - excl;
        hist[tid] = 0;                         // reuse as placement cursor
    }
    __syncthreads();

    // place into LDS stage, sorted by bucket
    #pragma unroll
    for (int k = 0; k < 8; ++k) {
        if (rr[k] >= 0) {
            int b = rr[k] >> BSHIFT;
            int kk = atomicAdd(&hist[b], 1);
            int pos = base_l[b] + kk;
            stage[pos] = make_int2(cc[k] | ((rr[k] & 1023) << 19), vv[k]);
            bIdA[pos] = (unsigned short)b;
        }
    }
    __syncthreads();

    // flush: destinations monotone within each bucket run -> coalesced
    #pragma unroll
    for (int k = 0; k < 8; ++k) {
        int i = tid + (k << 9);
        if (i < cnt) binned[gshift[bIdA[i]] + i] = stage[i];
    }
}

// ---------------- pass B: within-bucket row sort + per-row CSR offsets ----------------
// Computes its own CSR base (csr0 = sum of counts of buckets < b) via a
// 2-barrier shfl reduce over gcursor.
__global__ __launch_bounds__(1024) void passB(const int* __restrict__ gcursor,
                                              const int2* __restrict__ binned,
                                              int* __restrict__ row_start,
                                              int2* __restrict__ sedge) {
    __shared__ int lcnt[1024];
    __shared__ int wsum[17];
    int b = blockIdx.x;
    int t = threadIdx.x;
    int lane = t & 63;
    int wid = t >> 6;                     // 16 waves
    int base = b * BCAP;
    int cnt = gcursor[b];                 // edges in this bucket (count)

    // csr0 = sum of gcursor[j] for j < b (2 barriers, shfl reduce)
    int c = (t < b) ? gcursor[t] : 0;     // b <= 292 < NBUCKET, t<b safe
    #pragma unroll
    for (int off = 1; off < 64; off <<= 1) c += __shfl_xor(c, off);
    if (lane == 0) wsum[wid] = c;
    __syncthreads();
    if (t < 16) {
        int s = wsum[t];
        #pragma unroll
        for (int off = 1; off < 16; off <<= 1) s += __shfl_xor(s, off);
        if (t == 0) wsum[16] = s;
    }
    lcnt[t] = 0;
    __syncthreads();
    int csr0 = wsum[16];
    if (b == NBUCKET - 1 && t == 0) row_start[N_NODES_] = NNZ_;

    int lo[14], hv[14];
    #pragma unroll
    for (int k = 0; k < 14; ++k) {
        int i = t + (k << 10);
        if (i < cnt) {
            int2 p = ntload_i2(&binned[base + i]);
            lo[k] = p.x; hv[k] = p.y;
            atomicAdd(&lcnt[((unsigned)p.x >> 19) & 1023], 1);
        } else lo[k] = -1;                // bit31 never set in real entries
    }
    __syncthreads();

    // shfl-based inclusive scan over the 1024 counts
    int v = lcnt[t];
    int sv = v;
    #pragma unroll
    for (int off = 1; off < 64; off <<= 1) {
        int tmp = __shfl_up(sv, off);
        if (lane >= off) sv += tmp;
    }
    if (lane == 63) wsum[wid] = sv;       // wave totals
    __syncthreads();
    if (t < 16) {
        int ws = wsum[t];
        #pragma unroll
        for (int off = 1; off < 16; off <<= 1) {
            int tmp = __shfl_up(ws, off);
            if (t >= off) ws += tmp;
        }
        wsum[t] = ws;                     // inclusive wave-prefix
    }
    __syncthreads();
    int wbase = (wid == 0) ? 0 : wsum[wid - 1];
    int excl = wbase + sv - v;            // exclusive prefix for row t

    int gr = (b << BSHIFT) + t;
    if (gr < N_NODES_) row_start[gr] = csr0 + excl;
    lcnt[t] = excl;                       // reuse as placement cursor
    __syncthreads();

    #pragma unroll
    for (int k = 0; k < 14; ++k) {
        if (lo[k] >= 0) {
            int rl = ((unsigned)lo[k] >> 19) & 1023;
            int pos = atomicAdd(&lcnt[rl], 1);
            sedge[csr0 + pos] = make_int2(lo[k] & 0x7ffff, hv[k]);
        }
    }
}

// ---------------- CSR SpMM bf16, group-per-row ----------------
// 8-lane group owns one row; wave = 8 rows; block(256) = 32 rows.
// v11: edge loop unrolled x4 for deeper gather ILP.
// FUSE: out = (x0 + x1 + x2 + acc) * 0.25 written fp32 directly.
template<bool FUSE>
__global__ __launch_bounds__(256) void spmm_bf_t(const int* __restrict__ row_start,
                                                 const int2* __restrict__ sedge,
                                                 const uint4* __restrict__ x,
                                                 uint4* __restrict__ y,
                                                 const float4* __restrict__ u,
                                                 const float4* __restrict__ it,
                                                 const uint4* __restrict__ x1,
                                                 const uint4* __restrict__ x2,
                                                 float4* __restrict__ out) {
    int w = blockIdx.x * 32 + (threadIdx.x >> 3);   // row per 8-lane group
    int d = threadIdx.x & 7;                        // dim slice (8 elems)
    int s = row_start[w];
    int e = row_start[w + 1];
    float acc[8] = {0.f, 0.f, 0.f, 0.f, 0.f, 0.f, 0.f, 0.f};
    int i = s;
    for (; i + 3 < e; i += 4) {
        int2 p0 = sedge[i];
        int2 p1 = sedge[i + 1];
        int2 p2 = sedge[i + 2];
        int2 p3 = sedge[i + 3];
        uint4 r0 = x[((unsigned)p0.x << 3) + d];
        uint4 r1 = x[((unsigned)p1.x << 3) + d];
        uint4 r2 = x[((unsigned)p2.x << 3) + d];
        uint4 r3 = x[((unsigned)p3.x << 3) + d];
        fma8(acc, __int_as_float(p0.y), r0);
        fma8(acc, __int_as_float(p1.y), r1);
        fma8(acc, __int_as_float(p2.y), r2);
        fma8(acc, __int_as_float(p3.y), r3);
    }
    if (i + 1 < e) {
        int2 p0 = sedge[i];
        int2 p1 = sedge[i + 1];
        uint4 r0 = x[((unsigned)p0.x << 3) + d];
        uint4 r1 = x[((unsigned)p1.x << 3) + d];
        fma8(acc, __int_as_float(p0.y), r0);
        fma8(acc, __int_as_float(p1.y), r1);
        i += 2;
    }
    if (i < e) {
        int2 p0 = sedge[i];
        uint4 r0 = x[((unsigned)p0.x << 3) + d];
        fma8(acc, __int_as_float(p0.y), r0);
    }
    if (!FUSE) {
        y[(size_t)w * 8 + d] = pack8(acc);
    } else {
        const float4* src = (w < N_USERS) ? (u + (size_t)w * 16)
                                          : (it + (size_t)(w - N_USERS) * 16);
        float4 a  = ntload_f4(&src[2 * d]);
        float4 b2 = ntload_f4(&src[2 * d + 1]);
        float f0[8] = {a.x, a.y, a.z, a.w, b2.x, b2.y, b2.z, b2.w};
        float f1[8], f2[8];
        unpack8(f1, ntload_u4(&x1[(size_t)w * 8 + d]));
        unpack8(f2, x2[(size_t)w * 8 + d]);
        float o[8];
        #pragma unroll
        for (int k = 0; k < 8; ++k) o[k] = (f0[k] + f1[k] + f2[k] + acc[k]) * 0.25f;
        out[(size_t)w * 16 + 2 * d]     = make_float4(o[0], o[1], o[2], o[3]);
        out[(size_t)w * 16 + 2 * d + 1] = make_float4(o[4], o[5], o[6], o[7]);
    }
}

extern "C" void kernel_launch(void* const* d_in, const int* in_sizes, int n_in,
                              void* d_out, int out_size, void* d_ws, size_t ws_size,
                              hipStream_t stream) {
    const float* user_emb = (const float*)d_in[0];
    const float* item_emb = (const float*)d_in[1];
    const int*   rows     = (const int*)d_in[2];
    const int*   cols     = (const int*)d_in[3];
    const float* vals     = (const float*)d_in[4];
    float* out = (float*)d_out;

    const size_t nE = (size_t)N_NODES_ * DIM;   // 19.2M elems
    unsigned short* Abf = (unsigned short*)d_ws;            // 38.4 MB (x0)
    unsigned short* Bbf = Abf + nE;                         // 38.4 MB (x1)
    unsigned short* Cbf = Bbf + nE;                         // 38.4 MB (x2)
    int* row_start   = (int*)(Cbf + nE);                    // N+2 ints
    int* gcursor     = row_start + (N_NODES_ + 2);          // 512
    int2* binned = (int2*)(gcursor + 512);                  // 293*14336*8 = 33.6 MB
    int2* sedge  = binned + (size_t)NBUCKET * BCAP;         // 32 MB

    const int n_t8 = (int)(nE / 8);                         // 2.4M
    const int ew_grid   = (n_t8 + 255) / 256;               // 9375
    const int spmm_grid = N_NODES_ / 32;                    // 9375 (exact)

    // ---- build CSR: fixed-capacity bins (relative cursors, zero-init) ----
    hipMemsetAsync(gcursor, 0, NBUCKET * sizeof(int), stream);
    passA<<<PA_BLOCKS, 512, 0, stream>>>(rows, cols, vals, gcursor, binned);
    passB<<<NBUCKET, 1024, 0, stream>>>(gcursor, binned, row_start, sedge);

    // ---- x0 (bf16) ----
    init_bf<<<ew_grid, 256, 0, stream>>>((const float4*)user_emb, (const float4*)item_emb,
                                         (uint4*)Abf);
    // ---- 3 layers; layer 3 fuses the mean epilogue ----
    spmm_bf_t<false><<<spmm_grid, 256, 0, stream>>>(row_start, sedge, (const uint4*)Abf,
                                                    (uint4*)Bbf, nullptr, nullptr,
                                                    nullptr, nullptr, nullptr);
    spmm_bf_t<false><<<spmm_grid, 256, 0, stream>>>(row_start, sedge, (const uint4*)Bbf,
                                                    (uint4*)Cbf, nullptr, nullptr,
                                                    nullptr, nullptr, nullptr);
    spmm_bf_t<true><<<spmm_grid, 256, 0, stream>>>(row_start, sedge, (const uint4*)Cbf,
                                                   nullptr,
                                                   (const float4*)user_emb,
                                                   (const float4*)item_emb,
                                                   (const uint4*)Bbf, (const uint4*)Cbf,
                                                   (float4*)out);
}

// Round 17
// 511.333 us; speedup vs baseline: 1.1557x; 1.0061x over previous
//
#include <hip/hip_runtime.h>

// LightGCN propagation: out = mean(x0..x3), x_{k+1} = SpMM(COO, x_k)
// v12: passB latency cut: int4 paired edge loads (14 -> 7 iters), csr0 loads
//      issued early, csum/wsum split -> 5 barriers (was 6). row_start padded
//      to N+4 ints so binned is 16B-aligned.
//      spmm DECLARED STRUCTURAL (r16: x4 unroll nulled -> HBM-bound at
//      achievable concurrency; nt-hints nulled r8). passA untouched (control).

#define N_USERS  100000
#define N_ITEMS  200000
#define N_NODES_ 300000
#define DIM      64
#define NNZ_     4000000
#define BSHIFT   10
#define NBUCKET  ((N_NODES_ + 1023) >> 10)                // 293
#define BCAP     14336                                    // slots per bucket region
#define PA_CHUNK 4096
#define PA_BLOCKS ((NNZ_ + PA_CHUNK - 1) / PA_CHUNK)      // 977

// ---- non-temporal load wrappers ----
typedef float        f32x4 __attribute__((ext_vector_type(4)));
typedef unsigned int u32x4 __attribute__((ext_vector_type(4)));
typedef int          i32x4 __attribute__((ext_vector_type(4)));
__device__ __forceinline__ float4 ntload_f4(const float4* p) {
    f32x4 v = __builtin_nontemporal_load((const f32x4*)p);
    return make_float4(v.x, v.y, v.z, v.w);
}
__device__ __forceinline__ uint4 ntload_u4(const uint4* p) {
    u32x4 v = __builtin_nontemporal_load((const u32x4*)p);
    return make_uint4(v.x, v.y, v.z, v.w);
}
__device__ __forceinline__ int4 ntload_i4(const int4* p) {
    i32x4 v = __builtin_nontemporal_load((const i32x4*)p);
    return make_int4(v.x, v.y, v.z, v.w);
}

// ---- bf16 helpers (manual, RNE) ----
__device__ __forceinline__ unsigned short f2bf(float f) {
    unsigned u = __float_as_uint(f);
    unsigned r = 0x7fffu + ((u >> 16) & 1u);
    return (unsigned short)((u + r) >> 16);
}
__device__ __forceinline__ void fma8(float* acc, float v, uint4 r) {
    acc[0] = fmaf(v, __uint_as_float(r.x << 16), acc[0]);
    acc[1] = fmaf(v, __uint_as_float(r.x & 0xffff0000u), acc[1]);
    acc[2] = fmaf(v, __uint_as_float(r.y << 16), acc[2]);
    acc[3] = fmaf(v, __uint_as_float(r.y & 0xffff0000u), acc[3]);
    acc[4] = fmaf(v, __uint_as_float(r.z << 16), acc[4]);
    acc[5] = fmaf(v, __uint_as_float(r.z & 0xffff0000u), acc[5]);
    acc[6] = fmaf(v, __uint_as_float(r.w << 16), acc[6]);
    acc[7] = fmaf(v, __uint_as_float(r.w & 0xffff0000u), acc[7]);
}
__device__ __forceinline__ uint4 pack8(const float* f) {
    unsigned a = (unsigned)f2bf(f[0]) | ((unsigned)f2bf(f[1]) << 16);
    unsigned b = (unsigned)f2bf(f[2]) | ((unsigned)f2bf(f[3]) << 16);
    unsigned c = (unsigned)f2bf(f[4]) | ((unsigned)f2bf(f[5]) << 16);
    unsigned d = (unsigned)f2bf(f[6]) | ((unsigned)f2bf(f[7]) << 16);
    return make_uint4(a, b, c, d);
}
__device__ __forceinline__ void unpack8(float* f, uint4 r) {
    f[0] = __uint_as_float(r.x << 16); f[1] = __uint_as_float(r.x & 0xffff0000u);
    f[2] = __uint_as_float(r.y << 16); f[3] = __uint_as_float(r.y & 0xffff0000u);
    f[4] = __uint_as_float(r.z << 16); f[5] = __uint_as_float(r.z & 0xffff0000u);
    f[6] = __uint_as_float(r.w << 16); f[7] = __uint_as_float(r.w & 0xffff0000u);
}

// ---------------- init: Abf = bf16(concat(user,item)) ----------------
__global__ void init_bf(const float4* __restrict__ u, const float4* __restrict__ it,
                        uint4* __restrict__ Abf) {
    const int n_u = N_USERS * DIM / 8;   // 800000
    const int n_t = N_NODES_ * DIM / 8;  // 2400000
    int i = blockIdx.x * blockDim.x + threadIdx.x;
    if (i >= n_t) return;
    float4 a, b;
    if (i < n_u) { a = u[2 * i];           b = u[2 * i + 1]; }
    else         { int j = i - n_u; a = it[2 * j]; b = it[2 * j + 1]; }
    float f[8] = {a.x, a.y, a.z, a.w, b.x, b.y, b.z, b.w};
    Abf[i] = pack8(f);
}

// ---------------- pass A: block-local counting sort into row buckets ----------------
// 512 threads (rr[8]), shfl bucket scan. gcursor zero-init; atomicAdd returns
// RELATIVE offset, absolute = b*BCAP + rel. lo = col | (row_local10 << 19)
__global__ __launch_bounds__(512) void passA(const int* __restrict__ rows,
                                             const int* __restrict__ cols,
                                             const float* __restrict__ vals,
                                             int* __restrict__ gcursor,
                                             int2* __restrict__ binned) {
    __shared__ int  hist[NBUCKET];            // counts, then reused as cursor
    __shared__ int  base_l[NBUCKET];          // exclusive scan of hist
    __shared__ int  gshift[NBUCKET];          // abs_base[b] - base_l[b]
    __shared__ int  wsum[8];                  // wave totals for shfl scan
    __shared__ int2 stage[PA_CHUNK];          // 32 KB: chunk sorted by bucket
    __shared__ unsigned short bIdA[PA_CHUNK]; // 8 KB: bucket id per staged slot

    int tid = threadIdx.x;
    int lane = tid & 63;
    int wid = tid >> 6;                       // 8 waves
    int base = blockIdx.x * PA_CHUNK;
    int cnt = NNZ_ - base; if (cnt > PA_CHUNK) cnt = PA_CHUNK;

    for (int i = tid; i < NBUCKET; i += 512) hist[i] = 0;
    __syncthreads();

    int rr[8], cc[8], vv[8];
    #pragma unroll
    for (int k = 0; k < 8; ++k) {
        int i = tid + (k << 9);
        if (i < cnt) {
            int e = base + i;
            rr[k] = rows[e];
            cc[k] = cols[e];
            vv[k] = __float_as_int(vals[e]);
            atomicAdd(&hist[rr[k] >> BSHIFT], 1);
        } else rr[k] = -1;
    }
    __syncthreads();

    int cb = (tid < NBUCKET) ? hist[tid] : 0;
    int sv = cb;
    #pragma unroll
    for (int off = 1; off < 64; off <<= 1) {
        int tmp = __shfl_up(sv, off);
        if (lane >= off) sv += tmp;
    }
    if (lane == 63) wsum[wid] = sv;
    __syncthreads();
    if (tid < 8) {
        int ws = wsum[tid];
        #pragma unroll
        for (int off = 1; off < 8; off <<= 1) {
            int tmp = __shfl_up(ws, off);
            if (tid >= off) ws += tmp;
        }
        wsum[tid] = ws;                        // inclusive wave-prefix
    }
    __syncthreads();
    int wbase = wid ? wsum[wid - 1] : 0;
    int excl = wbase + sv - cb;               // exclusive prefix for bucket tid
    if (tid < NBUCKET) {
        base_l[tid] = excl;
        int g = cb ? atomicAdd(&gcursor[tid], cb) : 0;   // relative
        gshift[tid] = tid * BCAP + g - excl;
        hist[tid] = 0;                         // reuse as placement cursor
    }
    __syncthreads();

    #pragma unroll
    for (int k = 0; k < 8; ++k) {
        if (rr[k] >= 0) {
            int b = rr[k] >> BSHIFT;
            int kk = atomicAdd(&hist[b], 1);
            int pos = base_l[b] + kk;
            stage[pos] = make_int2(cc[k] | ((rr[k] & 1023) << 19), vv[k]);
            bIdA[pos] = (unsigned short)b;
        }
    }
    __syncthreads();

    #pragma unroll
    for (int k = 0; k < 8; ++k) {
        int i = tid + (k << 9);
        if (i < cnt) binned[gshift[bIdA[i]] + i] = stage[i];
    }
}

// ---------------- pass B: within-bucket row sort + per-row CSR offsets ----------------
// v12: int4 paired loads (7 iters), csr0 gcursor loads issued early, csum/wsum
// split -> 5 barriers. Computes csr0 = sum of counts of buckets < b in-block.
__global__ __launch_bounds__(1024) void passB(const int* __restrict__ gcursor,
                                              const int2* __restrict__ binned,
                                              int* __restrict__ row_start,
                                              int2* __restrict__ sedge) {
    __shared__ int lcnt[1024];
    __shared__ int csum[17];              // csr0 reduce
    __shared__ int wsum[16];              // lcnt scan wave totals
    int b = blockIdx.x;
    int t = threadIdx.x;
    int lane = t & 63;
    int wid = t >> 6;                     // 16 waves
    int base = b * BCAP;
    int cnt = gcursor[b];                 // edges in this bucket (count)
    int c = (t < b) ? gcursor[t] : 0;     // csr0 partials: issue loads early
    lcnt[t] = 0;
    if (b == NBUCKET - 1 && t == 0) row_start[N_NODES_] = NNZ_;
    __syncthreads();                      // B1: lcnt zeroed

    // load 2 edges per iter (int4) + LDS row-local histogram
    int npair = (cnt + 1) >> 1;
    const int4* b4 = (const int4*)(binned + base);   // 16B-aligned (BCAP even, base padded)
    int lo0[7], hv0[7], lo1[7], hv1[7];
    #pragma unroll
    for (int k = 0; k < 7; ++k) {
        int p = t + (k << 10);
        lo0[k] = -1; lo1[k] = -1;
        if (p < npair) {
            int4 q = ntload_i4(&b4[p]);
            lo0[k] = q.x; hv0[k] = q.y;
            atomicAdd(&lcnt[((unsigned)q.x >> 19) & 1023], 1);
            if (2 * p + 1 < cnt) {
                lo1[k] = q.z; hv1[k] = q.w;
                atomicAdd(&lcnt[((unsigned)q.z >> 19) & 1023], 1);
            }
        }
    }
    // csr0 wave-reduce overlaps the load loop epilogue
    #pragma unroll
    for (int off = 1; off < 64; off <<= 1) c += __shfl_xor(c, off);
    if (lane == 0) csum[wid] = c;
    __syncthreads();                      // B2: histogram done + csum parts ready

    if (t < 16) {
        int s = csum[t];
        #pragma unroll
        for (int off = 1; off < 16; off <<= 1) s += __shfl_xor(s, off);
        if (t == 0) csum[16] = s;
    }
    // lcnt inclusive scan (wave level)
    int v = lcnt[t];
    int sv = v;
    #pragma unroll
    for (int off = 1; off < 64; off <<= 1) {
        int tmp = __shfl_up(sv, off);
        if (lane >= off) sv += tmp;
    }
    if (lane == 63) wsum[wid] = sv;
    __syncthreads();                      // B3: wsum parts + csum[16] ready

    if (t < 16) {
        int ws = wsum[t];
        #pragma unroll
        for (int off = 1; off < 16; off <<= 1) {
            int tmp = __shfl_up(ws, off);
            if (t >= off) ws += tmp;
        }
        wsum[t] = ws;                     // inclusive wave-prefix
    }
    __syncthreads();                      // B4: wsum scanned

    int csr0 = csum[16];
    int wbase = (wid == 0) ? 0 : wsum[wid - 1];
    int excl = wbase + sv - v;            // exclusive prefix for row t
    int gr = (b << BSHIFT) + t;
    if (gr < N_NODES_) row_start[gr] = csr0 + excl;
    lcnt[t] = excl;                       // reuse as placement cursor
    __syncthreads();                      // B5: cursors ready

    #pragma unroll
    for (int k = 0; k < 7; ++k) {
        if (lo0[k] >= 0) {
            int rl = ((unsigned)lo0[k] >> 19) & 1023;
            int pos = atomicAdd(&lcnt[rl], 1);
            sedge[csr0 + pos] = make_int2(lo0[k] & 0x7ffff, hv0[k]);
        }
        if (lo1[k] >= 0) {
            int rl = ((unsigned)lo1[k] >> 19) & 1023;
            int pos = atomicAdd(&lcnt[rl], 1);
            sedge[csr0 + pos] = make_int2(lo1[k] & 0x7ffff, hv1[k]);
        }
    }
}

// ---------------- CSR SpMM bf16, group-per-row (STRUCTURAL — do not touch) ----------------
// 8-lane group owns one row; wave = 8 rows; block(256) = 32 rows.
// FUSE: out = (x0 + x1 + x2 + acc) * 0.25 written fp32 directly.
template<bool FUSE>
__global__ __launch_bounds__(256) void spmm_bf_t(const int* __restrict__ row_start,
                                                 const int2* __restrict__ sedge,
                                                 const uint4* __restrict__ x,
                                                 uint4* __restrict__ y,
                                                 const float4* __restrict__ u,
                                                 const float4* __restrict__ it,
                                                 const uint4* __restrict__ x1,
                                                 const uint4* __restrict__ x2,
                                                 float4* __restrict__ out) {
    int w = blockIdx.x * 32 + (threadIdx.x >> 3);   // row per 8-lane group
    int d = threadIdx.x & 7;                        // dim slice (8 elems)
    int s = row_start[w];
    int e = row_start[w + 1];
    float acc[8] = {0.f, 0.f, 0.f, 0.f, 0.f, 0.f, 0.f, 0.f};
    int i = s;
    for (; i + 3 < e; i += 4) {
        int2 p0 = sedge[i];
        int2 p1 = sedge[i + 1];
        int2 p2 = sedge[i + 2];
        int2 p3 = sedge[i + 3];
        uint4 r0 = x[((unsigned)p0.x << 3) + d];
        uint4 r1 = x[((unsigned)p1.x << 3) + d];
        uint4 r2 = x[((unsigned)p2.x << 3) + d];
        uint4 r3 = x[((unsigned)p3.x << 3) + d];
        fma8(acc, __int_as_float(p0.y), r0);
        fma8(acc, __int_as_float(p1.y), r1);
        fma8(acc, __int_as_float(p2.y), r2);
        fma8(acc, __int_as_float(p3.y), r3);
    }
    if (i + 1 < e) {
        int2 p0 = sedge[i];
        int2 p1 = sedge[i + 1];
        uint4 r0 = x[((unsigned)p0.x << 3) + d];
        uint4 r1 = x[((unsigned)p1.x << 3) + d];
        fma8(acc, __int_as_float(p0.y), r0);
        fma8(acc, __int_as_float(p1.y), r1);
        i += 2;
    }
    if (i < e) {
        int2 p0 = sedge[i];
        uint4 r0 = x[((unsigned)p0.x << 3) + d];
        fma8(acc, __int_as_float(p0.y), r0);
    }
    if (!FUSE) {
        y[(size_t)w * 8 + d] = pack8(acc);
    } else {
        const float4* src = (w < N_USERS) ? (u + (size_t)w * 16)
                                          : (it + (size_t)(w - N_USERS) * 16);
        float4 a  = ntload_f4(&src[2 * d]);
        float4 b2 = ntload_f4(&src[2 * d + 1]);
        float f0[8] = {a.x, a.y, a.z, a.w, b2.x, b2.y, b2.z, b2.w};
        float f1[8], f2[8];
        unpack8(f1, ntload_u4(&x1[(size_t)w * 8 + d]));
        unpack8(f2, x2[(size_t)w * 8 + d]);
        float o[8];
        #pragma unroll
        for (int k = 0; k < 8; ++k) o[k] = (f0[k] + f1[k] + f2[k] + acc[k]) * 0.25f;
        out[(size_t)w * 16 + 2 * d]     = make_float4(o[0], o[1], o[2], o[3]);
        out[(size_t)w * 16 + 2 * d + 1] = make_float4(o[4], o[5], o[6], o[7]);
    }
}

extern "C" void kernel_launch(void* const* d_in, const int* in_sizes, int n_in,
                              void* d_out, int out_size, void* d_ws, size_t ws_size,
                              hipStream_t stream) {
    const float* user_emb = (const float*)d_in[0];
    const float* item_emb = (const float*)d_in[1];
    const int*   rows     = (const int*)d_in[2];
    const int*   cols     = (const int*)d_in[3];
    const float* vals     = (const float*)d_in[4];
    float* out = (float*)d_out;

    const size_t nE = (size_t)N_NODES_ * DIM;   // 19.2M elems
    unsigned short* Abf = (unsigned short*)d_ws;            // 38.4 MB (x0)
    unsigned short* Bbf = Abf + nE;                         // 38.4 MB (x1)
    unsigned short* Cbf = Bbf + nE;                         // 38.4 MB (x2)
    int* row_start   = (int*)(Cbf + nE);                    // N+4 ints (padded for alignment)
    int* gcursor     = row_start + (N_NODES_ + 4);          // 512
    int2* binned = (int2*)(gcursor + 512);                  // 16B-aligned; 33.6 MB
    int2* sedge  = binned + (size_t)NBUCKET * BCAP;         // 32 MB

    const int n_t8 = (int)(nE / 8);                         // 2.4M
    const int ew_grid   = (n_t8 + 255) / 256;               // 9375
    const int spmm_grid = N_NODES_ / 32;                    // 9375 (exact)

    // ---- build CSR: fixed-capacity bins (relative cursors, zero-init) ----
    hipMemsetAsync(gcursor, 0, NBUCKET * sizeof(int), stream);
    passA<<<PA_BLOCKS, 512, 0, stream>>>(rows, cols, vals, gcursor, binned);
    passB<<<NBUCKET, 1024, 0, stream>>>(gcursor, binned, row_start, sedge);

    // ---- x0 (bf16) ----
    init_bf<<<ew_grid, 256, 0, stream>>>((const float4*)user_emb, (const float4*)item_emb,
                                         (uint4*)Abf);
    // ---- 3 layers; layer 3 fuses the mean epilogue ----
    spmm_bf_t<false><<<spmm_grid, 256, 0, stream>>>(row_start, sedge, (const uint4*)Abf,
                                                    (uint4*)Bbf, nullptr, nullptr,
                                                    nullptr, nullptr, nullptr);
    spmm_bf_t<false><<<spmm_grid, 256, 0, stream>>>(row_start, sedge, (const uint4*)Bbf,
                                                    (uint4*)Cbf, nullptr, nullptr,
                                                    nullptr, nullptr, nullptr);
    spmm_bf_t<true><<<spmm_grid, 256, 0, stream>>>(row_start, sedge, (const uint4*)Cbf,
                                                   nullptr,
                                                   (const float4*)user_emb,
                                                   (const float4*)item_emb,
                                                   (const uint4*)Bbf, (const uint4*)Cbf,
                                                   (float4*)out);
}